// Round 2
// baseline (292.728 us; speedup 1.0000x reference)
//
#include <hip/hip_runtime.h>

using v4f = float __attribute__((ext_vector_type(4)));

constexpr int NTOK = 32768;       // 16 * 2048 tokens
constexpr int DIMS = 64;
constexpr int KCODES = 1000;
constexpr int TPB = 128;          // tokens per argmin block
constexpr int CHUNK = 128;        // codes staged per LDS chunk
constexpr int NSPLIT = 4;         // K-splits (256 codes each, last padded)
constexpr int NCHUNK = 2;         // chunks per split
constexpr float BIG = 3.4e38f;

// ---------------------------------------------------------------- prep: zeros + codebook norms
__global__ void vq_prep(const float* __restrict__ emb, float* __restrict__ norms,
                        float* __restrict__ loss_accum, int* __restrict__ usage,
                        int* __restrict__ counter)
{
    int gid = blockIdx.x * 256 + threadIdx.x;
    if (gid == 0) { *loss_accum = 0.f; *counter = 0; }
    if (gid < KCODES) {
        usage[gid] = 0;
        const float* e = emb + gid * DIMS;
        float s = 0.f;
        #pragma unroll
        for (int d4 = 0; d4 < 16; ++d4) {
            v4f q = *reinterpret_cast<const v4f*>(e + d4 * 4);
            s = fmaf(q[0], q[0], s);
            s = fmaf(q[1], q[1], s);
            s = fmaf(q[2], q[2], s);
            s = fmaf(q[3], q[3], s);
        }
        norms[gid] = s;
    }
}

// ---------------------------------------------------------------- argmin: x from global/L1, e from swizzled LDS
__global__ __launch_bounds__(256, 4) void vq_argmin(
    const float* __restrict__ x, const float* __restrict__ emb,
    const float* __restrict__ norms,
    float* __restrict__ pval, int* __restrict__ pidx)
{
    __shared__ float es[CHUNK * DIMS];   // 32 KB, XOR-swizzled: word = c*64 + 4*(d4 ^ (c&7))
    __shared__ float ns[CHUNK];

    const int tid   = threadIdx.x;
    const int split = blockIdx.x >> 8;       // split-major: same tile's splits -> same XCD
    const int tblk  = blockIdx.x & 255;
    const int tok0  = tblk * TPB;
    const int b     = tok0 >> 11;
    const int l0    = tok0 & 2047;
    const float* xg = x + ((size_t)b << 17) + l0;

    const int ty = tid >> 4;   // 0..15: owns tokens ty*8 .. ty*8+7
    const int tx = tid & 15;   // owns codes tx + 16*j within chunk
    const float* xrow = xg + ty * 8;

    float minv[8];
    int   mini[8];
    #pragma unroll
    for (int i = 0; i < 8; ++i) { minv[i] = BIG; mini[i] = 0; }

    for (int cc = 0; cc < NCHUNK; ++cc) {
        const int cbase = split * (NCHUNK * CHUNK) + cc * CHUNK;
        __syncthreads();
        // stage e chunk swizzled (coalesced global read: consecutive tid -> consecutive 16B)
        #pragma unroll
        for (int it = 0; it < 8; ++it) {
            int f  = it * 256 + tid;
            int c  = f >> 4;
            int d4 = f & 15;
            int g  = cbase + c;
            v4f v = {0.f, 0.f, 0.f, 0.f};
            if (g < KCODES) v = *reinterpret_cast<const v4f*>(emb + g * DIMS + d4 * 4);
            *reinterpret_cast<v4f*>(es + c * 64 + 4 * (d4 ^ (c & 7))) = v;
        }
        if (tid < CHUNK) {
            int g = cbase + tid;
            ns[tid] = (g < KCODES) ? norms[g] : BIG;   // padded codes never win
        }
        __syncthreads();

        float acc[8][8];
        #pragma unroll
        for (int i = 0; i < 8; ++i)
            #pragma unroll
            for (int j = 0; j < 8; ++j) acc[i][j] = 0.f;

        #pragma unroll 4
        for (int d4 = 0; d4 < 16; ++d4) {
            const int d0 = d4 * 4;
            v4f xa[4], xb[4];
            #pragma unroll
            for (int dd = 0; dd < 4; ++dd) {
                xa[dd] = *reinterpret_cast<const v4f*>(xrow + (size_t)(d0 + dd) * 2048);
                xb[dd] = *reinterpret_cast<const v4f*>(xrow + (size_t)(d0 + dd) * 2048 + 4);
            }
            #pragma unroll
            for (int j = 0; j < 8; ++j) {
                const int c = tx + 16 * j;
                v4f ev = *reinterpret_cast<const v4f*>(es + c * 64 + 4 * (d4 ^ (c & 7)));
                #pragma unroll
                for (int dd = 0; dd < 4; ++dd) {
                    const float e = ev[dd];
                    acc[0][j] = fmaf(xa[dd][0], e, acc[0][j]);
                    acc[1][j] = fmaf(xa[dd][1], e, acc[1][j]);
                    acc[2][j] = fmaf(xa[dd][2], e, acc[2][j]);
                    acc[3][j] = fmaf(xa[dd][3], e, acc[3][j]);
                    acc[4][j] = fmaf(xb[dd][0], e, acc[4][j]);
                    acc[5][j] = fmaf(xb[dd][1], e, acc[5][j]);
                    acc[6][j] = fmaf(xb[dd][2], e, acc[6][j]);
                    acc[7][j] = fmaf(xb[dd][3], e, acc[7][j]);
                }
            }
        }

        // fold chunk into running argmin (ascending code index; strict < keeps first min)
        #pragma unroll
        for (int j = 0; j < 8; ++j) {
            const int c  = tx + 16 * j;
            const float nv = ns[c];
            const int gi = cbase + c;
            #pragma unroll
            for (int i = 0; i < 8; ++i) {
                float dist = fmaf(-2.f, acc[i][j], nv);
                if (dist < minv[i]) { minv[i] = dist; mini[i] = gi; }
            }
        }
    }

    // cross-tx (16-lane group) argmin merge, lexicographic (val, idx)
    #pragma unroll
    for (int i = 0; i < 8; ++i) {
        float v = minv[i];
        int  ix = mini[i];
        #pragma unroll
        for (int off = 8; off >= 1; off >>= 1) {
            float vo = __shfl_xor(v, off);
            int   io = __shfl_xor(ix, off);
            if (vo < v || (vo == v && io < ix)) { v = vo; ix = io; }
        }
        if (tx == 0) {
            int token = tok0 + ty * 8 + i;
            pval[split * NTOK + token] = v;
            pidx[split * NTOK + token] = ix;
        }
    }
}

// ---------------------------------------------------------------- merge + gather + loss + usage + finalize
__global__ __launch_bounds__(128) void vq_output(
    const float* __restrict__ x, const float* __restrict__ emb,
    const float* __restrict__ pval, const int* __restrict__ pidx,
    float* __restrict__ out, float* __restrict__ idx_f,
    float* __restrict__ loss_accum, int* __restrict__ usage,
    int* __restrict__ counter, float* __restrict__ o_scalars)
{
    const int tid   = threadIdx.x;
    const int token = blockIdx.x * 128 + tid;

    // merge K-splits (ascending split -> strict < keeps lowest idx on ties)
    float bv = pval[token];
    int   bi = pidx[token];
    #pragma unroll
    for (int s = 1; s < NSPLIT; ++s) {
        float v = pval[s * NTOK + token];
        int   i2 = pidx[s * NTOK + token];
        if (v < bv) { bv = v; bi = i2; }
    }
    idx_f[token] = (float)bi;
    atomicOr(&usage[bi], 1);   // device-scope: safe across XCDs

    const int b = token >> 11, l = token & 2047;
    const float* xb = x   + ((size_t)b << 17) + l;
    float*       ob = out + ((size_t)b << 17) + l;
    const float* e  = emb + bi * DIMS;

    float lsum = 0.f;
    #pragma unroll 8
    for (int d = 0; d < DIMS; ++d) {
        float xv   = xb[(size_t)d * 2048];
        float diff = e[d] - xv;            // quantized - inputs
        lsum = fmaf(diff, diff, lsum);
        ob[(size_t)d * 2048] = xv + diff;  // exact STE forward
    }

    #pragma unroll
    for (int off = 32; off >= 1; off >>= 1) lsum += __shfl_xor(lsum, off);
    __shared__ float bsum[2];
    if ((tid & 63) == 0) bsum[tid >> 6] = lsum;
    __syncthreads();
    if (tid == 0) atomicAdd(loss_accum, bsum[0] + bsum[1]);

    // last-block finalize (ticket)
    __threadfence();
    __shared__ int last;
    if (tid == 0) last = (atomicAdd(counter, 1) == (int)gridDim.x - 1);
    __syncthreads();
    if (last) {
        int c = 0;
        #pragma unroll
        for (int k = 0; k < 8; ++k) {
            int u = tid * 8 + k;
            if (u < KCODES) c += atomicAdd(&usage[u], 0);  // coherent read at L2 point
        }
        #pragma unroll
        for (int off = 32; off >= 1; off >>= 1) c += __shfl_xor(c, off);
        __shared__ int csum[2];
        if ((tid & 63) == 0) csum[tid >> 6] = c;
        __syncthreads();
        if (tid == 0) {
            float s = atomicAdd(loss_accum, 0.0f);   // coherent read
            float m = s / 2097152.0f;                // mean over B*L*D
            o_scalars[0] = 11.0f * m;                // q_latent + 10 * e_latent
            o_scalars[1] = (float)(csum[0] + csum[1]);
        }
    }
}

// ---------------------------------------------------------------- launch
extern "C" void kernel_launch(void* const* d_in, const int* in_sizes, int n_in,
                              void* d_out, int out_size, void* d_ws, size_t ws_size,
                              hipStream_t stream)
{
    const float* x   = (const float*)d_in[0];   // [16, 64, 2048]
    const float* emb = (const float*)d_in[1];   // [1000, 64]

    float* o       = (float*)d_out;
    float* out     = o;                 // 2097152 floats, [B, D, L]
    float* o_scal  = o + 2097152;       // loss, usage
    float* o_idx   = o + 2097154;       // 32768 floats

    char*  ws         = (char*)d_ws;
    float* loss_accum = (float*)(ws);
    int*   counter    = (int*)(ws + 8);
    int*   usage      = (int*)(ws + 64);
    float* norms      = (float*)(ws + 4160);
    float* pval       = (float*)(ws + 8192);
    int*   pidx       = (int*)(ws + 8192 + NSPLIT * NTOK * sizeof(float));
    // total ws use: ~1.03 MB

    vq_prep<<<4, 256, 0, stream>>>(emb, norms, loss_accum, usage, counter);
    vq_argmin<<<NSPLIT * 256, 256, 0, stream>>>(x, emb, norms, pval, pidx);
    vq_output<<<NTOK / 128, 128, 0, stream>>>(x, emb, pval, pidx, out, o_idx,
                                              loss_accum, usage, counter, o_scal);
}

// Round 3
// 212.714 us; speedup vs baseline: 1.3762x; 1.3762x over previous
//
#include <hip/hip_runtime.h>

using v4f = float __attribute__((ext_vector_type(4)));

constexpr int NTOK = 32768;       // 16 * 2048 tokens
constexpr int DIMS = 64;
constexpr int KCODES = 1000;
constexpr int TPB = 128;          // tokens per argmin block
constexpr int CHUNK = 128;        // codes staged per LDS chunk
constexpr int NSPLIT = 2;         // K-splits (512 codes each, last padded to 1024)
constexpr int CPS = 4;            // chunks per split
constexpr float BIG = 3.4e38f;

// ---------------------------------------------------------------- prep: zeros + codebook norms
__global__ void vq_prep(const float* __restrict__ emb, float* __restrict__ norms,
                        float* __restrict__ loss_accum, int* __restrict__ usage,
                        int* __restrict__ counter)
{
    int gid = blockIdx.x * 256 + threadIdx.x;
    if (gid == 0) { *loss_accum = 0.f; *counter = 0; }
    if (gid < KCODES) {
        usage[gid] = 0;
        const float* e = emb + gid * DIMS;
        float s = 0.f;
        #pragma unroll
        for (int d4 = 0; d4 < 16; ++d4) {
            v4f q = *reinterpret_cast<const v4f*>(e + d4 * 4);
            s = fmaf(q[0], q[0], s);
            s = fmaf(q[1], q[1], s);
            s = fmaf(q[2], q[2], s);
            s = fmaf(q[3], q[3], s);
        }
        norms[gid] = s;
    }
}

// ---------------------------------------------------------------- argmin: x from global (L1-resident tile),
//                                                                   e from LDS with proven 68-pad layout
__global__ __launch_bounds__(256, 2) void vq_argmin(
    const float* __restrict__ x, const float* __restrict__ emb,
    const float* __restrict__ norms,
    float* __restrict__ pval, int* __restrict__ pidx)
{
    __shared__ float es[CHUNK][68];   // [code][d], pad 64->68: r1-proven 0-conflict layout
    __shared__ float ns[CHUNK];

    const int tid   = threadIdx.x;
    const int split = blockIdx.x >> 8;   // split-major: bid and bid+256 land on same XCD (same mod 8)
    const int tblk  = blockIdx.x & 255;
    const int tok0  = tblk * TPB;
    const int b     = tok0 >> 11;
    const int l0    = tok0 & 2047;

    const int ty = tid >> 4;   // 0..15: owns tokens ty*8 .. ty*8+7
    const int tx = tid & 15;   // owns codes tx + 16*j within chunk
    const float* xrow = x + ((size_t)b << 17) + l0 + ty * 8;  // x[b][d][...] = xrow[d*2048 + t]

    float minv[8];
    int   mini[8];
    #pragma unroll
    for (int i = 0; i < 8; ++i) { minv[i] = BIG; mini[i] = 0; }

    for (int cc = 0; cc < CPS; ++cc) {
        const int cbase = split * (CPS * CHUNK) + cc * CHUNK;
        __syncthreads();
        // stage e chunk (coalesced global float4 reads; 16-lane phases keep LDS writes 2-way/free)
        #pragma unroll
        for (int it = 0; it < 8; ++it) {
            int f  = it * 256 + tid;
            int c  = f >> 4;
            int d4 = f & 15;
            int g  = cbase + c;
            v4f v = {0.f, 0.f, 0.f, 0.f};
            if (g < KCODES) v = *reinterpret_cast<const v4f*>(emb + g * DIMS + d4 * 4);
            *reinterpret_cast<v4f*>(&es[c][d4 * 4]) = v;
        }
        if (tid < CHUNK) {
            int g = cbase + tid;
            ns[tid] = (g < KCODES) ? norms[g] : BIG;   // padded codes never win
        }
        __syncthreads();

        float acc[8][8];
        #pragma unroll
        for (int i = 0; i < 8; ++i)
            #pragma unroll
            for (int j = 0; j < 8; ++j) acc[i][j] = 0.f;

        #pragma unroll 4
        for (int d4 = 0; d4 < 16; ++d4) {
            const int d0 = d4 * 4;
            v4f xa[4], xb[4];
            #pragma unroll
            for (int dd = 0; dd < 4; ++dd) {
                xa[dd] = *reinterpret_cast<const v4f*>(xrow + (size_t)(d0 + dd) * 2048);
                xb[dd] = *reinterpret_cast<const v4f*>(xrow + (size_t)(d0 + dd) * 2048 + 4);
            }
            #pragma unroll
            for (int j = 0; j < 8; ++j) {
                v4f ev = *reinterpret_cast<const v4f*>(&es[tx + 16 * j][d0]);
                #pragma unroll
                for (int dd = 0; dd < 4; ++dd) {
                    const float e = ev[dd];
                    acc[0][j] = fmaf(xa[dd][0], e, acc[0][j]);
                    acc[1][j] = fmaf(xa[dd][1], e, acc[1][j]);
                    acc[2][j] = fmaf(xa[dd][2], e, acc[2][j]);
                    acc[3][j] = fmaf(xa[dd][3], e, acc[3][j]);
                    acc[4][j] = fmaf(xb[dd][0], e, acc[4][j]);
                    acc[5][j] = fmaf(xb[dd][1], e, acc[5][j]);
                    acc[6][j] = fmaf(xb[dd][2], e, acc[6][j]);
                    acc[7][j] = fmaf(xb[dd][3], e, acc[7][j]);
                }
            }
        }

        // fold chunk into running argmin (ascending code index; strict < keeps first min)
        #pragma unroll
        for (int j = 0; j < 8; ++j) {
            const int c  = tx + 16 * j;
            const float nv = ns[c];
            const int gi = cbase + c;
            #pragma unroll
            for (int i = 0; i < 8; ++i) {
                float dist = fmaf(-2.f, acc[i][j], nv);
                if (dist < minv[i]) { minv[i] = dist; mini[i] = gi; }
            }
        }
    }

    // cross-tx (16-lane group) argmin merge, lexicographic (val, idx)
    #pragma unroll
    for (int i = 0; i < 8; ++i) {
        float v = minv[i];
        int  ix = mini[i];
        #pragma unroll
        for (int off = 8; off >= 1; off >>= 1) {
            float vo = __shfl_xor(v, off);
            int   io = __shfl_xor(ix, off);
            if (vo < v || (vo == v && io < ix)) { v = vo; ix = io; }
        }
        if (tx == 0) {
            int token = tok0 + ty * 8 + i;
            pval[split * NTOK + token] = v;
            pidx[split * NTOK + token] = ix;
        }
    }
}

// ---------------------------------------------------------------- merge + gather + loss + usage + finalize
// 2D mapping: block = 64 tokens x 4 dim-groups (16 dims each) -> 512 blocks, 8 waves/CU
__global__ __launch_bounds__(256) void vq_output(
    const float* __restrict__ x, const float* __restrict__ emb,
    const float* __restrict__ pval, const int* __restrict__ pidx,
    float* __restrict__ out, float* __restrict__ idx_f,
    float* __restrict__ loss_accum, int* __restrict__ usage,
    int* __restrict__ counter, float* __restrict__ o_scalars)
{
    const int tid   = threadIdx.x;
    const int ll    = tid & 63;          // token lane (coalesced along L)
    const int dg    = tid >> 6;          // dim-group 0..3 -> dims dg*16 .. dg*16+15
    const int token = blockIdx.x * 64 + ll;

    // merge K-splits (ascending split; strict < keeps lowest idx on ties)
    float bv = pval[token];
    int   bi = pidx[token];
    #pragma unroll
    for (int s = 1; s < NSPLIT; ++s) {
        float v  = pval[s * NTOK + token];
        int   i2 = pidx[s * NTOK + token];
        if (v < bv) { bv = v; bi = i2; }
    }
    if (dg == 0) {
        idx_f[token] = (float)bi;
        atomicOr(&usage[bi], 1);         // device-scope: safe across XCDs
    }

    const int b = token >> 11, l = token & 2047;
    const float* xb = x   + ((size_t)b << 17) + l + (size_t)(dg * 16) * 2048;
    float*       ob = out + ((size_t)b << 17) + l + (size_t)(dg * 16) * 2048;
    const float* e  = emb + bi * DIMS + dg * 16;

    float lsum = 0.f;
    #pragma unroll
    for (int q4 = 0; q4 < 4; ++q4) {
        v4f q = *reinterpret_cast<const v4f*>(e + q4 * 4);
        #pragma unroll
        for (int k = 0; k < 4; ++k) {
            const int d = q4 * 4 + k;
            float xv   = xb[(size_t)d * 2048];
            float diff = q[k] - xv;            // quantized - inputs
            lsum = fmaf(diff, diff, lsum);
            ob[(size_t)d * 2048] = xv + diff;  // inputs + (quantized - inputs): exact STE forward
        }
    }

    #pragma unroll
    for (int off = 32; off >= 1; off >>= 1) lsum += __shfl_xor(lsum, off);
    __shared__ float bsum[4];
    if ((tid & 63) == 0) bsum[tid >> 6] = lsum;
    __syncthreads();
    if (tid == 0) atomicAdd(loss_accum, bsum[0] + bsum[1] + bsum[2] + bsum[3]);

    // last-block finalize (ticket)
    __threadfence();
    __shared__ int last;
    if (tid == 0) last = (atomicAdd(counter, 1) == (int)gridDim.x - 1);
    __syncthreads();
    if (last) {
        int c = 0;
        #pragma unroll
        for (int k = 0; k < 4; ++k) {
            int u = tid * 4 + k;
            if (u < KCODES) c += atomicAdd(&usage[u], 0);   // coherent read at L2 point
        }
        #pragma unroll
        for (int off = 32; off >= 1; off >>= 1) c += __shfl_xor(c, off);
        __shared__ int csum[4];
        if ((tid & 63) == 0) csum[tid >> 6] = c;
        __syncthreads();
        if (tid == 0) {
            float s = atomicAdd(loss_accum, 0.0f);   // coherent read
            float m = s / 2097152.0f;                // mean over B*L*D
            o_scalars[0] = 11.0f * m;                // q_latent + 10 * e_latent
            o_scalars[1] = (float)(csum[0] + csum[1] + csum[2] + csum[3]);
        }
    }
}

// ---------------------------------------------------------------- launch
extern "C" void kernel_launch(void* const* d_in, const int* in_sizes, int n_in,
                              void* d_out, int out_size, void* d_ws, size_t ws_size,
                              hipStream_t stream)
{
    const float* x   = (const float*)d_in[0];   // [16, 64, 2048]
    const float* emb = (const float*)d_in[1];   // [1000, 64]

    float* o       = (float*)d_out;
    float* out     = o;                 // 2097152 floats, [B, D, L]
    float* o_scal  = o + 2097152;       // loss, usage
    float* o_idx   = o + 2097154;       // 32768 floats

    char*  ws         = (char*)d_ws;
    float* loss_accum = (float*)(ws);
    int*   counter    = (int*)(ws + 8);
    int*   usage      = (int*)(ws + 64);
    float* norms      = (float*)(ws + 4160);
    float* pval       = (float*)(ws + 8192);
    int*   pidx       = (int*)(ws + 8192 + NSPLIT * NTOK * sizeof(float));
    // total ws use: ~520 KB

    vq_prep<<<4, 256, 0, stream>>>(emb, norms, loss_accum, usage, counter);
    vq_argmin<<<NSPLIT * 256, 256, 0, stream>>>(x, emb, norms, pval, pidx);
    vq_output<<<NTOK / 64, 256, 0, stream>>>(x, emb, pval, pidx, out, o_idx,
                                             loss_accum, usage, counter, o_scal);
}